// Round 10
// baseline (172.397 us; speedup 1.0000x reference)
//
#include <hip/hip_runtime.h>
#include <stdint.h>

#define THR  1.0f
#define BETA 0.95f
#define SX   4096.0f            // x scale (2^12) -> no fp16 denormal flush
#define SW   512.0f             // W scale (2^9)
#define SINV (1.0f / (4096.0f * 512.0f))
#define W1N  (128 * 784)

typedef __attribute__((ext_vector_type(8)))  _Float16 f16x8;
typedef __attribute__((ext_vector_type(16))) float    f32x16;
typedef __attribute__((ext_vector_type(4)))  float    fvec4;

__device__ __forceinline__ void gll16(const float* g, float* l){
  __builtin_amdgcn_global_load_lds((const __attribute__((address_space(1))) void*)g,
                                   (__attribute__((address_space(3))) void*)l, 16, 0, 0);
}

// 2-term RNE fp16 split of scaled W1 in per-16k fragment order:
// fragment (gks 0..48, nf 0..3, term 0..1) = 512 f16 (1KB); lane (kg*32+r)
// holds 8 f16 for col h=nf*32+r, k=gks*16+kg*8+0..7.
__global__ void split_w1(const float* __restrict__ W1, _Float16* __restrict__ wB){
  int i = blockIdx.x * 256 + threadIdx.x;
  if (i < W1N) {
    int h = i / 784, k = i % 784;
    float v = W1[i] * SW;
    _Float16 hi = (_Float16)v;
    _Float16 lo = (_Float16)(v - (float)hi);
    int ks = k >> 4, kg = (k >> 3) & 1, j = k & 7, nf = h >> 5, r = h & 31;
    int base = ((ks * 4 + nf) * 2) * 512 + (kg * 32 + r) * 8 + j;
    wB[base]       = hi;   // term 0
    wB[base + 512] = lo;   // term 1
  }
}

// cur1[m][h] = sum_k x[m][k]*W1[h][k] + b1[h] (scaled acc; bias in epilogue).
// Block: 4 waves, tile 128m x 128n; wave w: rows w*32..+32, all 128 cols.
// 49 slabs of 16k, 4-deep LDS rotation (16KB each: A 8KB + B 8KB), 64KB total.
// Fragment-major LDS for BOTH operands: every LDS access is lane*16B-contiguous
// (conflict-free, no swizzle); the A "transpose" is in the per-lane global addr.
// vmcnt(12): compute(s) runs with slabs s+1..s+3 in flight (staged 1-3 phases
// ahead -> the waited-on slab landed long ago; near-zero stall).
__launch_bounds__(256, 2)
__global__ void gemm1(const float* __restrict__ x,
                      const float* __restrict__ wBf,   // wB viewed as float*
                      const float* __restrict__ b1,
                      float* __restrict__ cur1,
                      long row0){
  __shared__ float lds[16384];            // 4 x 4096 floats (16KB slabs)
  const int lane = threadIdx.x & 63;
  const int w    = threadIdx.x >> 6;
  const long blk_row0 = row0 + (long)blockIdx.x * 128;
  const int r  = lane & 31;
  const int kg = lane >> 5;

  // per-lane invariant source bases
  const float* xA  = x + (blk_row0 + w * 32 + r) * 784 + kg * 8;  // this wave's A frag rows
  const float* wBs = wBf + w * 512 + lane * 4;                    // this wave's 2 B frags

  // stage slab s into buffer bb: 4 gll16/wave (A frags (w,h0/h1), B frags 2w,2w+1)
  #define STAGE(bb, s) {                                                     \
    gll16(xA  + (s) * 16,       &lds[(bb) * 4096 + (w * 2 + 0) * 256]);      \
    gll16(xA  + (s) * 16 + 4,   &lds[(bb) * 4096 + (w * 2 + 1) * 256]);      \
    gll16(wBs + (s) * 2048,     &lds[(bb) * 4096 + 2048 + (w * 2 + 0) * 256]); \
    gll16(wBs + (s) * 2048 + 256, &lds[(bb) * 4096 + 2048 + (w * 2 + 1) * 256]); }

  // consume slab in buffer bb: 10 ds_read_b128 + split + 12 MFMA
  #define COMPUTE(bb) {                                                      \
    f16x8 b[8];                                                              \
    _Pragma("unroll") for (int f = 0; f < 8; ++f)                            \
      b[f] = *(const f16x8*)&lds[(bb) * 4096 + 2048 + f * 256 + lane * 4];   \
    fvec4 a0 = *(const fvec4*)&lds[(bb) * 4096 + (w * 2 + 0) * 256 + lane * 4]; \
    fvec4 a1 = *(const fvec4*)&lds[(bb) * 4096 + (w * 2 + 1) * 256 + lane * 4]; \
    f16x8 ah, al;                                                            \
    _Pragma("unroll") for (int j = 0; j < 8; ++j) {                          \
      float v = ((j < 4) ? a0[j] : a1[j - 4]) * SX;                          \
      _Float16 hh = (_Float16)v;                                             \
      ah[j] = hh; al[j] = (_Float16)(v - (float)hh);                         \
    }                                                                        \
    _Pragma("unroll") for (int nf = 0; nf < 4; ++nf) {                       \
      acc[nf] = __builtin_amdgcn_mfma_f32_32x32x16_f16(ah, b[nf * 2],     acc[nf], 0, 0, 0); \
      acc[nf] = __builtin_amdgcn_mfma_f32_32x32x16_f16(ah, b[nf * 2 + 1], acc[nf], 0, 0, 0); \
      acc[nf] = __builtin_amdgcn_mfma_f32_32x32x16_f16(al, b[nf * 2],     acc[nf], 0, 0, 0); \
    } }

  #define FENCE_A() { __builtin_amdgcn_sched_barrier(0);                     \
    asm volatile("s_waitcnt lgkmcnt(0)" ::: "memory");                       \
    __builtin_amdgcn_s_barrier();                                            \
    asm volatile("" ::: "memory"); }
  #define FENCE_B(vm) {                                                      \
    asm volatile("s_waitcnt vmcnt(" #vm ")" ::: "memory");                   \
    __builtin_amdgcn_s_barrier();                                            \
    asm volatile("" ::: "memory");                                           \
    __builtin_amdgcn_sched_barrier(0); }

  f32x16 acc[4] = {};

  // prologue: fill the 4-deep pipe (16 loads/wave in flight)
  STAGE(0, 0); STAGE(1, 1); STAGE(2, 2); STAGE(3, 3);
  FENCE_B(12);                            // slab 0 landed; 1..3 in flight
  COMPUTE(0);

  // main: slabs 1..44 (stage s+3, always 3 slabs / 12 loads in flight)
  for (int q = 0; q < 11; ++q) {
    const int s = 4 * q + 1;
    FENCE_A(); STAGE(0, s + 3); FENCE_B(12); COMPUTE(1);
    FENCE_A(); STAGE(1, s + 4); FENCE_B(12); COMPUTE(2);
    FENCE_A(); STAGE(2, s + 5); FENCE_B(12); COMPUTE(3);
    FENCE_A(); STAGE(3, s + 6); FENCE_B(12); COMPUTE(0);
  }

  // peeled drain: slabs 45..48
  FENCE_A(); STAGE(0, 48); FENCE_B(12); COMPUTE(1);
  FENCE_A();               FENCE_B(8);  COMPUTE(2);
  FENCE_A();               FENCE_B(4);  COMPUTE(3);
  FENCE_A();               FENCE_B(0);  COMPUTE(0);

  // C/D layout (m74/m101-verified): col = lane&31, row = (reg&3)+8*(reg>>2)+4*(lane>>5)
  float b1v[4];
  #pragma unroll
  for (int nf = 0; nf < 4; ++nf) b1v[nf] = b1[nf * 32 + r];
  long m0 = (long)blockIdx.x * 128 + w * 32;
  #pragma unroll
  for (int nf = 0; nf < 4; ++nf)
    #pragma unroll
    for (int reg = 0; reg < 16; ++reg) {
      int rr = (reg & 3) + 8 * (reg >> 2) + 4 * kg;
      cur1[(m0 + rr) * 128 + nf * 32 + r] = acc[nf][reg] * SINV + b1v[nf];
    }
  #undef STAGE
  #undef COMPUTE
  #undef FENCE_A
  #undef FENCE_B
}

// LIF recurrence + layer 2 (bias1 already folded into cur1).
__launch_bounds__(256)
__global__ void lif(const float* __restrict__ cur1,
                    const float* __restrict__ W2,
                    const float* __restrict__ b2,
                    float* __restrict__ out,
                    float* __restrict__ state1,
                    float* __restrict__ state2,
                    int t0, int tn){
  const int lane = threadIdx.x & 63;
  const int b = blockIdx.x * 4 + (threadIdx.x >> 6);
  const int o = lane & 15;
  const int c = lane >> 4;

  float wv[32];
  #pragma unroll
  for (int j = 0; j < 32; ++j) wv[j] = 0.f;
  if (o < 10) {
    #pragma unroll
    for (int j = 0; j < 32; ++j) wv[j] = W2[o * 128 + c * 32 + j];
  }
  float b2v = (lane < 10) ? b2[lane] : 0.f;

  float mem1a, mem1b, mem2;
  if (t0 == 0) { mem1a = 0.f; mem1b = 0.f; mem2 = 0.f; }
  else {
    mem1a = state1[b * 128 + lane];
    mem1b = state1[b * 128 + 64 + lane];
    mem2  = (lane < 10) ? state2[b * 10 + lane] : 0.f;
  }

  for (int t = t0; t < tn; ++t) {
    long base = ((long)(t - t0) * 4096 + b) * 128;
    float c1a = cur1[base + lane];
    float c1b = cur1[base + 64 + lane];
    float r1a = (mem1a > THR) ? THR : 0.f;
    float r1b = (mem1b > THR) ? THR : 0.f;
    mem1a = BETA * mem1a + c1a - r1a;
    mem1b = BETA * mem1b + c1b - r1b;

    uint64_t mA = __ballot(mem1a > THR);
    uint64_t mB = __ballot(mem1b > THR);
    uint64_t m64 = (c & 2) ? mB : mA;
    uint32_t bits = (uint32_t)(m64 >> ((c & 1) << 5));

    float s = 0.f;
    #pragma unroll
    for (int j = 0; j < 32; ++j)
      s = fmaf((float)((bits >> j) & 1u), wv[j], s);   // bfe+cvt+fma
    s += __shfl_xor(s, 16);
    s += __shfl_xor(s, 32);

    if (lane < 10) {
      float cur2 = s + b2v;
      float r2 = (mem2 > THR) ? THR : 0.f;
      mem2 = BETA * mem2 + cur2 - r2;
      float s2 = (mem2 > THR) ? 1.f : 0.f;
      long ob = (long)t * 40960 + (long)b * 10 + lane;
      out[ob] = s2;
      out[1228800 + ob] = mem2;
    }
  }

  if (tn < 30) {
    state1[b * 128 + lane] = mem1a;
    state1[b * 128 + 64 + lane] = mem1b;
    if (lane < 10) state2[b * 10 + lane] = mem2;
  }
}

extern "C" void kernel_launch(void* const* d_in, const int* in_sizes, int n_in,
                              void* d_out, int out_size, void* d_ws, size_t ws_size,
                              hipStream_t stream) {
  const float* x  = (const float*)d_in[0];
  const float* W1 = (const float*)d_in[1];
  const float* b1 = (const float*)d_in[2];
  const float* W2 = (const float*)d_in[3];
  const float* b2 = (const float*)d_in[4];
  float* out = (float*)d_out;

  const int T = 30, B = 4096;

  char* ws = (char*)d_ws;
  _Float16* wB = (_Float16*)ws;                  // 49*8*512 fp16 = 392KB
  size_t off = (size_t)49 * 8 * 512 * sizeof(_Float16);
  off = (off + 255) & ~(size_t)255;
  float* state1 = (float*)(ws + off); off += (size_t)B * 128 * 4;
  float* state2 = (float*)(ws + off); off += (size_t)B * 10 * 4;
  off = (off + 255) & ~(size_t)255;
  float* cur1 = (float*)(ws + off);

  size_t per_t = (size_t)B * 128 * 4;
  size_t avail = (ws_size > off) ? (ws_size - off) : 0;
  int CH = (int)(avail / per_t);
  if (CH > T) CH = T;
  if (CH < 1) CH = 1;

  split_w1<<<(W1N + 255) / 256, 256, 0, stream>>>(W1, wB);

  for (int t0 = 0; t0 < T; t0 += CH) {
    int tn = (t0 + CH < T) ? (t0 + CH) : T;
    int mrows = (tn - t0) * B;                   // multiple of 4096 -> multiple of 128
    gemm1<<<mrows / 128, 256, 0, stream>>>(x, (const float*)wB, b1, cur1, (long)t0 * B);
    lif<<<B / 4, 256, 0, stream>>>(cur1, W2, b2, out, state1, state2, t0, tn);
  }
}

// Round 13
// 171.061 us; speedup vs baseline: 1.0078x; 1.0078x over previous
//
#include <hip/hip_runtime.h>
#include <stdint.h>

#define THR  1.0f
#define BETA 0.95f
#define SX   4096.0f            // x scale (2^12) -> no fp16 denormal flush
#define SW   512.0f             // W scale (2^9)
#define SINV (1.0f / (4096.0f * 512.0f))
#define W1N  (128 * 784)

typedef __attribute__((ext_vector_type(8)))  _Float16 f16x8;
typedef __attribute__((ext_vector_type(16))) float    f32x16;
typedef __attribute__((ext_vector_type(4)))  float    fvec4;

__device__ __forceinline__ void gll16(const float* g, float* l){
  __builtin_amdgcn_global_load_lds((const __attribute__((address_space(1))) void*)g,
                                   (__attribute__((address_space(3))) void*)l, 16, 0, 0);
}

// 2-term RNE fp16 split of scaled W1 in per-16k fragment order:
// fragment (gks 0..48, nf 0..3, term 0..1) = 512 f16 (1KB); lane (kg*32+r)
// holds 8 f16 for col h=nf*32+r, k=gks*16+kg*8+0..7.
__global__ void split_w1(const float* __restrict__ W1, _Float16* __restrict__ wB){
  int i = blockIdx.x * 256 + threadIdx.x;
  if (i < W1N) {
    int h = i / 784, k = i % 784;
    float v = W1[i] * SW;
    _Float16 hi = (_Float16)v;
    _Float16 lo = (_Float16)(v - (float)hi);
    int ks = k >> 4, kg = (k >> 3) & 1, j = k & 7, nf = h >> 5, r = h & 31;
    int base = ((ks * 4 + nf) * 2) * 512 + (kg * 32 + r) * 8 + j;
    wB[base]       = hi;   // term 0
    wB[base + 512] = lo;   // term 1
  }
}

// cur1[m][h] = sum_k x[m][k]*W1[h][k] + b1[h] (scaled acc; bias in epilogue).
// Block: 4 waves, tile 128m x 128n; wave w: rows w*32..+32, all 128 cols.
// 49 slabs of 16k; 5-deep LDS rotation (16KB slabs, 80KB total, 2 blocks/CU).
// Phase s = [STAGE(s+3) -> vmcnt(12) -> s_barrier -> COMPUTE(s)]: ONE barrier
// per phase, no lgkm drains. Hazard-free: while any wave reads buf s%5, the
// possibly-unlanded writes span slabs s+1..s+4 -> bufs (s+1..s+4)%5, never
// s%5 (depth 5 = distance 3 + 2 is the minimum safe depth).
__launch_bounds__(256, 2)
__global__ void gemm1(const float* __restrict__ x,
                      const float* __restrict__ wBf,   // wB viewed as float*
                      const float* __restrict__ b1,
                      float* __restrict__ cur1,
                      long row0){
  __shared__ float lds[20480];            // 5 x 4096 floats (16KB slabs)
  const int lane = threadIdx.x & 63;
  const int w    = threadIdx.x >> 6;
  const long blk_row0 = row0 + (long)blockIdx.x * 128;
  const int r  = lane & 31;
  const int kg = lane >> 5;

  // per-lane invariant source bases
  const float* xA  = x + (blk_row0 + w * 32 + r) * 784 + kg * 8;  // wave's A rows
  const float* wBs = wBf + w * 512 + lane * 4;                    // wave's 2 B frags

  // stage slab s into buffer bb: 4 gll16/wave (A frags w*2,w*2+1; B frags 2w,2w+1)
  #define STAGE(bb, s) {                                                     \
    gll16(xA  + (s) * 16,         &lds[(bb) * 4096 + (w * 2 + 0) * 256]);    \
    gll16(xA  + (s) * 16 + 4,     &lds[(bb) * 4096 + (w * 2 + 1) * 256]);    \
    gll16(wBs + (s) * 2048,       &lds[(bb) * 4096 + 2048 + (w * 2 + 0) * 256]); \
    gll16(wBs + (s) * 2048 + 256, &lds[(bb) * 4096 + 2048 + (w * 2 + 1) * 256]); }

  // consume slab in buffer bb: 10 ds_read_b128 + split + 12 MFMA
  #define CPH(bb) {                                                          \
    f16x8 b[8];                                                              \
    _Pragma("unroll") for (int f = 0; f < 8; ++f)                            \
      b[f] = *(const f16x8*)&lds[(bb) * 4096 + 2048 + f * 256 + lane * 4];   \
    fvec4 a0 = *(const fvec4*)&lds[(bb) * 4096 + (w * 2 + 0) * 256 + lane * 4]; \
    fvec4 a1 = *(const fvec4*)&lds[(bb) * 4096 + (w * 2 + 1) * 256 + lane * 4]; \
    f16x8 ah, al;                                                            \
    _Pragma("unroll") for (int j = 0; j < 8; ++j) {                          \
      float v = ((j < 4) ? a0[j] : a1[j - 4]) * SX;                          \
      _Float16 hh = (_Float16)v;                                             \
      ah[j] = hh; al[j] = (_Float16)(v - (float)hh);                         \
    }                                                                        \
    _Pragma("unroll") for (int nf = 0; nf < 4; ++nf) {                       \
      acc[nf] = __builtin_amdgcn_mfma_f32_32x32x16_f16(ah, b[nf * 2],     acc[nf], 0, 0, 0); \
      acc[nf] = __builtin_amdgcn_mfma_f32_32x32x16_f16(ah, b[nf * 2 + 1], acc[nf], 0, 0, 0); \
      acc[nf] = __builtin_amdgcn_mfma_f32_32x32x16_f16(al, b[nf * 2],     acc[nf], 0, 0, 0); \
    } }

  // single fence per phase: counted vmcnt + barrier (+ compiler fences)
  #define VMB(vm) {                                                          \
    asm volatile("s_waitcnt vmcnt(" #vm ")" ::: "memory");                   \
    __builtin_amdgcn_s_barrier();                                            \
    asm volatile("" ::: "memory");                                           \
    __builtin_amdgcn_sched_barrier(0); }

  f32x16 acc[4] = {};

  // prologue: stage slabs 0..2 (12 loads/wave in flight)
  STAGE(0, 0); STAGE(1, 1); STAGE(2, 2);

  // phases 0..44 (9 groups of 5; stage slab s+3, compute slab s)
  for (int g = 0; g < 9; ++g) {
    const int s5 = 5 * g;
    STAGE(3, s5 + 3); VMB(12); CPH(0);
    STAGE(4, s5 + 4); VMB(12); CPH(1);
    STAGE(0, s5 + 5); VMB(12); CPH(2);
    STAGE(1, s5 + 6); VMB(12); CPH(3);
    STAGE(2, s5 + 7); VMB(12); CPH(4);
  }
  // phase 45 (stage last slab 48), then drains 46..48
  STAGE(3, 48); VMB(12); CPH(0);
  VMB(8);  CPH(1);
  VMB(4);  CPH(2);
  VMB(0);  CPH(3);

  // C/D layout (m74/m101-verified): col = lane&31, row = (reg&3)+8*(reg>>2)+4*(lane>>5)
  float b1v[4];
  #pragma unroll
  for (int nf = 0; nf < 4; ++nf) b1v[nf] = b1[nf * 32 + r];
  long m0 = (long)blockIdx.x * 128 + w * 32;
  #pragma unroll
  for (int nf = 0; nf < 4; ++nf)
    #pragma unroll
    for (int reg = 0; reg < 16; ++reg) {
      int rr = (reg & 3) + 8 * (reg >> 2) + 4 * kg;
      cur1[(m0 + rr) * 128 + nf * 32 + r] = acc[nf][reg] * SINV + b1v[nf];
    }
  #undef STAGE
  #undef CPH
  #undef VMB
}

// LIF recurrence + layer 2 (bias1 already folded into cur1).
__launch_bounds__(256)
__global__ void lif(const float* __restrict__ cur1,
                    const float* __restrict__ W2,
                    const float* __restrict__ b2,
                    float* __restrict__ out,
                    float* __restrict__ state1,
                    float* __restrict__ state2,
                    int t0, int tn){
  const int lane = threadIdx.x & 63;
  const int b = blockIdx.x * 4 + (threadIdx.x >> 6);
  const int o = lane & 15;
  const int c = lane >> 4;

  float wv[32];
  #pragma unroll
  for (int j = 0; j < 32; ++j) wv[j] = 0.f;
  if (o < 10) {
    #pragma unroll
    for (int j = 0; j < 32; ++j) wv[j] = W2[o * 128 + c * 32 + j];
  }
  float b2v = (lane < 10) ? b2[lane] : 0.f;

  float mem1a, mem1b, mem2;
  if (t0 == 0) { mem1a = 0.f; mem1b = 0.f; mem2 = 0.f; }
  else {
    mem1a = state1[b * 128 + lane];
    mem1b = state1[b * 128 + 64 + lane];
    mem2  = (lane < 10) ? state2[b * 10 + lane] : 0.f;
  }

  for (int t = t0; t < tn; ++t) {
    long base = ((long)(t - t0) * 4096 + b) * 128;
    float c1a = cur1[base + lane];
    float c1b = cur1[base + 64 + lane];
    float r1a = (mem1a > THR) ? THR : 0.f;
    float r1b = (mem1b > THR) ? THR : 0.f;
    mem1a = BETA * mem1a + c1a - r1a;
    mem1b = BETA * mem1b + c1b - r1b;

    uint64_t mA = __ballot(mem1a > THR);
    uint64_t mB = __ballot(mem1b > THR);
    uint64_t m64 = (c & 2) ? mB : mA;
    uint32_t bits = (uint32_t)(m64 >> ((c & 1) << 5));

    float s = 0.f;
    #pragma unroll
    for (int j = 0; j < 32; ++j)
      s = fmaf((float)((bits >> j) & 1u), wv[j], s);   // bfe+cvt+fma
    s += __shfl_xor(s, 16);
    s += __shfl_xor(s, 32);

    if (lane < 10) {
      float cur2 = s + b2v;
      float r2 = (mem2 > THR) ? THR : 0.f;
      mem2 = BETA * mem2 + cur2 - r2;
      float s2 = (mem2 > THR) ? 1.f : 0.f;
      long ob = (long)t * 40960 + (long)b * 10 + lane;
      out[ob] = s2;
      out[1228800 + ob] = mem2;
    }
  }

  if (tn < 30) {
    state1[b * 128 + lane] = mem1a;
    state1[b * 128 + 64 + lane] = mem1b;
    if (lane < 10) state2[b * 10 + lane] = mem2;
  }
}

extern "C" void kernel_launch(void* const* d_in, const int* in_sizes, int n_in,
                              void* d_out, int out_size, void* d_ws, size_t ws_size,
                              hipStream_t stream) {
  const float* x  = (const float*)d_in[0];
  const float* W1 = (const float*)d_in[1];
  const float* b1 = (const float*)d_in[2];
  const float* W2 = (const float*)d_in[3];
  const float* b2 = (const float*)d_in[4];
  float* out = (float*)d_out;

  const int T = 30, B = 4096;

  char* ws = (char*)d_ws;
  _Float16* wB = (_Float16*)ws;                  // 49*8*512 fp16 = 392KB
  size_t off = (size_t)49 * 8 * 512 * sizeof(_Float16);
  off = (off + 255) & ~(size_t)255;
  float* state1 = (float*)(ws + off); off += (size_t)B * 128 * 4;
  float* state2 = (float*)(ws + off); off += (size_t)B * 10 * 4;
  off = (off + 255) & ~(size_t)255;
  float* cur1 = (float*)(ws + off);

  size_t per_t = (size_t)B * 128 * 4;
  size_t avail = (ws_size > off) ? (ws_size - off) : 0;
  int CH = (int)(avail / per_t);
  if (CH > T) CH = T;
  if (CH < 1) CH = 1;

  split_w1<<<(W1N + 255) / 256, 256, 0, stream>>>(W1, wB);

  for (int t0 = 0; t0 < T; t0 += CH) {
    int tn = (t0 + CH < T) ? (t0 + CH) : T;
    int mrows = (tn - t0) * B;                   // multiple of 4096 -> multiple of 128
    gemm1<<<mrows / 128, 256, 0, stream>>>(x, (const float*)wB, b1, cur1, (long)t0 * B);
    lif<<<B / 4, 256, 0, stream>>>(cur1, W2, b2, out, state1, state2, t0, tn);
  }
}